// Round 1
// baseline (1712.095 us; speedup 1.0000x reference)
//
#include <hip/hip_runtime.h>
#include <stdint.h>

#define DEV __device__ __forceinline__

typedef unsigned short u16;
typedef __attribute__((ext_vector_type(8))) short short8;
typedef __attribute__((ext_vector_type(4))) float floatx4;

#define B_ 2
#define T_ 1024
#define C_ 768
#define H_ 12
#define L_ 6
#define V_ 32000
#define F_ 3072
#define M_ 2048   // B*T

DEV float bf2f(u16 s) { unsigned int u = ((unsigned int)s) << 16; float f; __builtin_memcpy(&f, &u, 4); return f; }
DEV u16 f2bf(float f) {
  unsigned int u; __builtin_memcpy(&u, &f, 4);
  u += 0x7FFFu + ((u >> 16) & 1u);   // round-to-nearest-even
  return (u16)(u >> 16);
}

// async global->LDS, 16B per lane. lptr must be wave-uniform; HW adds lane*16.
DEV void gload16(const void* g, void* l) {
  __builtin_amdgcn_global_load_lds(
      (__attribute__((address_space(1))) void*)(uintptr_t)g,
      (__attribute__((address_space(3))) void*)(unsigned int)(uintptr_t)l,
      16, 0, 0);
}

// ---------------- transpose + f32->bf16 convert: src[R][Cc] -> dst[Cc][R] ----------------
__global__ __launch_bounds__(256) void transpose_f32_bf16(
    const float* __restrict__ src, u16* __restrict__ dst, int R, int Cc) {
  __shared__ float tile[32][33];
  size_t zoff = (size_t)blockIdx.z * R * Cc;
  const float* s = src + zoff;
  u16* d = dst + zoff;
  int c0 = blockIdx.x * 32, r0 = blockIdx.y * 32;
  int tx = threadIdx.x & 31, ty = threadIdx.x >> 5;
#pragma unroll
  for (int i = 0; i < 4; i++)
    tile[ty + 8 * i][tx] = s[(size_t)(r0 + ty + 8 * i) * Cc + (c0 + tx)];
  __syncthreads();
#pragma unroll
  for (int i = 0; i < 4; i++)
    d[(size_t)(c0 + ty + 8 * i) * R + (r0 + tx)] = f2bf(tile[tx][ty + 8 * i]);
}

// ---------------- embedding: x[row][c] = tok[idx[row]][c] + pos[row%T][c] ----------------
__global__ __launch_bounds__(256) void embed_kernel(
    const int* __restrict__ idx, const float* __restrict__ tok,
    const float* __restrict__ pos, float* __restrict__ x) {
  int row = blockIdx.x;
  int t = row & (T_ - 1);
  int tk = idx[row];
  const float* tp = tok + (size_t)tk * C_;
  const float* pp = pos + (size_t)t * C_;
  float* xp = x + (size_t)row * C_;
  for (int c = threadIdx.x; c < C_; c += 256) xp[c] = tp[c] + pp[c];
}

// ---------------- layernorm: f32 in -> bf16 out ----------------
__global__ __launch_bounds__(256) void ln_kernel(
    const float* __restrict__ x, const float* __restrict__ g,
    const float* __restrict__ b, u16* __restrict__ out) {
  int row = blockIdx.x;
  int tid = threadIdx.x;
  const float* xp = x + (size_t)row * C_;
  float v0 = xp[tid], v1 = xp[tid + 256], v2 = xp[tid + 512];
  float s = v0 + v1 + v2;
  float ss = v0 * v0 + v1 * v1 + v2 * v2;
#pragma unroll
  for (int o = 32; o > 0; o >>= 1) { s += __shfl_down(s, o); ss += __shfl_down(ss, o); }
  __shared__ float red[8];
  int wid = tid >> 6;
  if ((tid & 63) == 0) { red[wid] = s; red[4 + wid] = ss; }
  __syncthreads();
  float tot = red[0] + red[1] + red[2] + red[3];
  float tss = red[4] + red[5] + red[6] + red[7];
  float mean = tot * (1.f / C_);
  float var = tss * (1.f / C_) - mean * mean;
  float rstd = rsqrtf(var + 1e-5f);
  u16* op = out + (size_t)row * C_;
  op[tid]       = f2bf((v0 - mean) * rstd * g[tid]       + b[tid]);
  op[tid + 256] = f2bf((v1 - mean) * rstd * g[tid + 256] + b[tid + 256]);
  op[tid + 512] = f2bf((v2 - mean) * rstd * g[tid + 512] + b[tid + 512]);
}

// ---------------- GEMM: A[M,K](bf16) @ B[K,N] via BT[N,K](bf16) ----------------
// OUTMODE: 0 = bf16 out, 1 = f32 residual accumulate (fout += acc+bias), 2 = f32 out
template <int BIAS, int RELU, int OUTMODE>
__global__ __launch_bounds__(256) void gemm_bt(
    const u16* __restrict__ A,
    const u16* __restrict__ BT0, const u16* __restrict__ BT1, const u16* __restrict__ BT2,
    const float* __restrict__ bias,
    u16* __restrict__ ob0, u16* __restrict__ ob1, u16* __restrict__ ob2,
    float* __restrict__ fout, int N, int K) {
  const u16* BT = blockIdx.z == 0 ? BT0 : (blockIdx.z == 1 ? BT1 : BT2);
  u16* ob = blockIdx.z == 0 ? ob0 : (blockIdx.z == 1 ? ob1 : ob2);
  __shared__ __align__(16) u16 As[128 * 32];
  __shared__ __align__(16) u16 Bs[128 * 32];
  int m0 = blockIdx.x * 128, n0 = blockIdx.y * 128;
  int tid = threadIdx.x;
  int lane = tid & 63, w = tid >> 6;
  int wm = w >> 1, wn = w & 1;
  int rr = lane & 15, kq = (lane >> 4) << 3;
  floatx4 zero = {0.f, 0.f, 0.f, 0.f};
  floatx4 acc[4][4];
#pragma unroll
  for (int i = 0; i < 4; i++)
#pragma unroll
    for (int j = 0; j < 4; j++) acc[i][j] = zero;

  int arow = tid >> 2, acol = (tid & 3) << 3;
  const u16* Ag = A + (size_t)(m0 + arow) * K + acol;
  const u16* Bg = BT + (size_t)(n0 + arow) * K + acol;

  for (int k0 = 0; k0 < K; k0 += 32) {
    gload16(Ag + k0,                  As + (size_t)(w * 64) * 8);
    gload16(Ag + (size_t)64 * K + k0, As + (size_t)(256 + w * 64) * 8);
    gload16(Bg + k0,                  Bs + (size_t)(w * 64) * 8);
    gload16(Bg + (size_t)64 * K + k0, Bs + (size_t)(256 + w * 64) * 8);
    __syncthreads();
    short8 af[4], bf[4];
#pragma unroll
    for (int i = 0; i < 4; i++)
      af[i] = *(const short8*)&As[(wm * 64 + i * 16 + rr) * 32 + kq];
#pragma unroll
    for (int j = 0; j < 4; j++)
      bf[j] = *(const short8*)&Bs[(wn * 64 + j * 16 + rr) * 32 + kq];
#pragma unroll
    for (int i = 0; i < 4; i++)
#pragma unroll
      for (int j = 0; j < 4; j++)
        acc[i][j] = __builtin_amdgcn_mfma_f32_16x16x32_bf16(af[i], bf[j], acc[i][j], 0, 0, 0);
    __syncthreads();
  }

  int cb = n0 + wn * 64;
  int rb = m0 + wm * 64;
#pragma unroll
  for (int i = 0; i < 4; i++) {
#pragma unroll
    for (int j = 0; j < 4; j++) {
      int col = cb + j * 16 + rr;
      float bv = 0.f;
      if (BIAS) bv = bias[col];
#pragma unroll
      for (int r = 0; r < 4; r++) {
        int row = rb + i * 16 + ((lane >> 4) << 2) + r;
        float val = acc[i][j][r] + bv;
        if (RELU) val = fmaxf(val, 0.f);
        size_t o = (size_t)row * N + col;
        if (OUTMODE == 0) ob[o] = f2bf(val);
        else if (OUTMODE == 1) fout[o] += val;
        else fout[o] = val;
      }
    }
  }
}

// ---------------- fused causal attention, 1 wave per 16 query rows ----------------
__global__ __launch_bounds__(64) void attn_kernel(
    const u16* __restrict__ q, const u16* __restrict__ k,
    const u16* __restrict__ v, u16* __restrict__ o) {
  __shared__ __align__(16) u16 P_s[16 * 32];
  int idx = blockIdx.x;
  int qt = idx & 63;           // T/16 = 64 q-tiles
  int h = (idx >> 6) % H_;
  int b = idx / (64 * H_);
  int q0 = qt << 4;
  int lane = threadIdx.x;
  int rr = lane & 15, qg = lane >> 4, kq = qg << 3;

  const u16* qb = q + (size_t)(b * T_ + q0 + rr) * C_ + h * 64;
  short8 qf0 = *(const short8*)(qb + kq);
  short8 qf1 = *(const short8*)(qb + 32 + kq);

  float m_r[4], l_r[4];
  floatx4 zero = {0.f, 0.f, 0.f, 0.f};
  floatx4 oacc[4];
#pragma unroll
  for (int r = 0; r < 4; r++) { m_r[r] = -1e30f; l_r[r] = 0.f; }
#pragma unroll
  for (int d = 0; d < 4; d++) oacc[d] = zero;

  for (int kt0 = 0; kt0 <= q0 + 15; kt0 += 32) {
    floatx4 s[2];
#pragma unroll
    for (int c = 0; c < 2; c++) {
      int key = kt0 + c * 16 + rr;
      int keyc = key < T_ ? key : T_ - 1;
      const u16* kb = k + (size_t)(b * T_ + keyc) * C_ + h * 64;
      short8 kf0 = *(const short8*)(kb + kq);
      short8 kf1 = *(const short8*)(kb + 32 + kq);
      floatx4 z = zero;
      z = __builtin_amdgcn_mfma_f32_16x16x32_bf16(qf0, kf0, z, 0, 0, 0);
      z = __builtin_amdgcn_mfma_f32_16x16x32_bf16(qf1, kf1, z, 0, 0, 0);
      s[c] = z;
    }
    float esc[4];
#pragma unroll
    for (int r = 0; r < 4; r++) {
      int qpos = q0 + qg * 4 + r;
#pragma unroll
      for (int c = 0; c < 2; c++) {
        int kpos = kt0 + c * 16 + rr;
        float val = s[c][r] * 0.125f;    // 1/sqrt(64)
        s[c][r] = (kpos <= qpos) ? val : -1e30f;
      }
      float mx = fmaxf(s[0][r], s[1][r]);
      mx = fmaxf(mx, __shfl_xor(mx, 1));
      mx = fmaxf(mx, __shfl_xor(mx, 2));
      mx = fmaxf(mx, __shfl_xor(mx, 4));
      mx = fmaxf(mx, __shfl_xor(mx, 8));
      float mn = fmaxf(m_r[r], mx);
      esc[r] = exp2f((m_r[r] - mn) * 1.44269504f);
      m_r[r] = mn;
      float p0 = exp2f((s[0][r] - mn) * 1.44269504f);
      float p1 = exp2f((s[1][r] - mn) * 1.44269504f);
      float ps = p0 + p1;
      ps += __shfl_xor(ps, 1);
      ps += __shfl_xor(ps, 2);
      ps += __shfl_xor(ps, 4);
      ps += __shfl_xor(ps, 8);
      l_r[r] = l_r[r] * esc[r] + ps;
      int prow = qg * 4 + r;
      P_s[prow * 32 + rr]      = f2bf(p0);
      P_s[prow * 32 + 16 + rr] = f2bf(p1);
    }
#pragma unroll
    for (int d = 0; d < 4; d++)
#pragma unroll
      for (int r = 0; r < 4; r++) oacc[d][r] *= esc[r];
    __syncthreads();
    short8 pa = *(const short8*)&P_s[rr * 32 + kq];
#pragma unroll
    for (int d = 0; d < 4; d++) {
      short8 vf;
#pragma unroll
      for (int j = 0; j < 8; j++) {
        int key = kt0 + kq + j;
        int keyc = key < T_ ? key : T_ - 1;
        vf[j] = (short)v[(size_t)(b * T_ + keyc) * C_ + h * 64 + d * 16 + rr];
      }
      oacc[d] = __builtin_amdgcn_mfma_f32_16x16x32_bf16(pa, vf, oacc[d], 0, 0, 0);
    }
    __syncthreads();
  }
  u16* obp = o + (size_t)(b * T_ + q0) * C_ + h * 64;
#pragma unroll
  for (int d = 0; d < 4; d++)
#pragma unroll
    for (int r = 0; r < 4; r++) {
      int row = qg * 4 + r;
      obp[(size_t)row * C_ + d * 16 + rr] = f2bf(oacc[d][r] / l_r[r]);
    }
}

extern "C" void kernel_launch(void* const* d_in, const int* in_sizes, int n_in,
                              void* d_out, int out_size, void* d_ws, size_t ws_size,
                              hipStream_t stream) {
  (void)in_sizes; (void)n_in; (void)out_size; (void)ws_size;
  const int*   xidx = (const int*)d_in[0];
  const float* tok  = (const float*)d_in[1];
  const float* pos  = (const float*)d_in[2];
  const float* ln1g = (const float*)d_in[3];
  const float* ln1b = (const float*)d_in[4];
  const float* wq   = (const float*)d_in[5];
  const float* wk   = (const float*)d_in[6];
  const float* wv   = (const float*)d_in[7];
  const float* wo   = (const float*)d_in[8];
  const float* bo   = (const float*)d_in[9];
  const float* ln2g = (const float*)d_in[10];
  const float* ln2b = (const float*)d_in[11];
  const float* w1   = (const float*)d_in[12];
  const float* b1   = (const float*)d_in[13];
  const float* w2   = (const float*)d_in[14];
  const float* b2   = (const float*)d_in[15];
  const float* lnfg = (const float*)d_in[16];
  const float* lnfb = (const float*)d_in[17];
  const float* wp   = (const float*)d_in[18];
  const float* bp   = (const float*)d_in[19];

  char* ws = (char*)d_ws;
  size_t off = 0;
  auto alloc = [&](size_t bytes) { char* p = ws + off; off += (bytes + 255) & ~(size_t)255; return p; };
  u16* wqT = (u16*)alloc((size_t)L_ * C_ * C_ * 2);
  u16* wkT = (u16*)alloc((size_t)L_ * C_ * C_ * 2);
  u16* wvT = (u16*)alloc((size_t)L_ * C_ * C_ * 2);
  u16* woT = (u16*)alloc((size_t)L_ * C_ * C_ * 2);
  u16* w1T = (u16*)alloc((size_t)L_ * C_ * F_ * 2);
  u16* w2T = (u16*)alloc((size_t)L_ * C_ * F_ * 2);
  u16* wpT = (u16*)alloc((size_t)C_ * V_ * 2);
  float* x = (float*)alloc((size_t)M_ * C_ * 4);
  u16* hb  = (u16*)alloc((size_t)M_ * C_ * 2);
  u16* qb  = (u16*)alloc((size_t)M_ * C_ * 2);
  u16* kb  = (u16*)alloc((size_t)M_ * C_ * 2);
  u16* vb  = (u16*)alloc((size_t)M_ * C_ * 2);
  u16* aob = (u16*)alloc((size_t)M_ * C_ * 2);
  u16* mb  = (u16*)alloc((size_t)M_ * F_ * 2);

  dim3 blk(256);
  transpose_f32_bf16<<<dim3(C_ / 32, C_ / 32, L_), blk, 0, stream>>>(wq, wqT, C_, C_);
  transpose_f32_bf16<<<dim3(C_ / 32, C_ / 32, L_), blk, 0, stream>>>(wk, wkT, C_, C_);
  transpose_f32_bf16<<<dim3(C_ / 32, C_ / 32, L_), blk, 0, stream>>>(wv, wvT, C_, C_);
  transpose_f32_bf16<<<dim3(C_ / 32, C_ / 32, L_), blk, 0, stream>>>(wo, woT, C_, C_);
  transpose_f32_bf16<<<dim3(F_ / 32, C_ / 32, L_), blk, 0, stream>>>(w1, w1T, C_, F_);
  transpose_f32_bf16<<<dim3(C_ / 32, F_ / 32, L_), blk, 0, stream>>>(w2, w2T, F_, C_);
  transpose_f32_bf16<<<dim3(V_ / 32, C_ / 32, 1), blk, 0, stream>>>(wp, wpT, C_, V_);
  embed_kernel<<<M_, blk, 0, stream>>>(xidx, tok, pos, x);

  for (int l = 0; l < L_; ++l) {
    size_t wOff = (size_t)l * C_ * C_;
    size_t fOff = (size_t)l * C_ * F_;
    ln_kernel<<<M_, blk, 0, stream>>>(x, ln1g + l * C_, ln1b + l * C_, hb);
    gemm_bt<0, 0, 0><<<dim3(M_ / 128, C_ / 128, 3), blk, 0, stream>>>(
        hb, wqT + wOff, wkT + wOff, wvT + wOff, nullptr, qb, kb, vb, nullptr, C_, C_);
    attn_kernel<<<B_ * H_ * (T_ / 16), dim3(64), 0, stream>>>(qb, kb, vb, aob);
    gemm_bt<1, 0, 1><<<dim3(M_ / 128, C_ / 128, 1), blk, 0, stream>>>(
        aob, woT + wOff, woT + wOff, woT + wOff, bo + l * C_,
        nullptr, nullptr, nullptr, x, C_, C_);
    ln_kernel<<<M_, blk, 0, stream>>>(x, ln2g + l * C_, ln2b + l * C_, hb);
    gemm_bt<1, 1, 0><<<dim3(M_ / 128, F_ / 128, 1), blk, 0, stream>>>(
        hb, w1T + fOff, w1T + fOff, w1T + fOff, b1 + l * F_,
        mb, mb, mb, nullptr, F_, C_);
    gemm_bt<1, 0, 1><<<dim3(M_ / 128, C_ / 128, 1), blk, 0, stream>>>(
        mb, w2T + fOff, w2T + fOff, w2T + fOff, b2 + l * C_,
        nullptr, nullptr, nullptr, x, C_, F_);
  }
  ln_kernel<<<M_, blk, 0, stream>>>(x, lnfg, lnfb, hb);
  gemm_bt<1, 0, 2><<<dim3(M_ / 128, V_ / 128, 1), blk, 0, stream>>>(
      hb, wpT, wpT, wpT, bp, nullptr, nullptr, nullptr, (float*)d_out, V_, C_);
}

// Round 2
// 1514.213 us; speedup vs baseline: 1.1307x; 1.1307x over previous
//
#include <hip/hip_runtime.h>
#include <stdint.h>

#define DEV __device__ __forceinline__

typedef unsigned short u16;
typedef __attribute__((ext_vector_type(8))) short short8;
typedef __attribute__((ext_vector_type(4))) float floatx4;

#define B_ 2
#define T_ 1024
#define C_ 768
#define H_ 12
#define L_ 6
#define V_ 32000
#define F_ 3072
#define M_ 2048   // B*T

DEV float bf2f(u16 s) { unsigned int u = ((unsigned int)s) << 16; float f; __builtin_memcpy(&f, &u, 4); return f; }
DEV u16 f2bf(float f) {
  unsigned int u; __builtin_memcpy(&u, &f, 4);
  u += 0x7FFFu + ((u >> 16) & 1u);   // round-to-nearest-even
  return (u16)(u >> 16);
}

// async global->LDS, 16B per lane. LDS ptr must be wave-uniform; HW adds lane*16.
DEV void gload16(const void* g, void* l) {
  __builtin_amdgcn_global_load_lds(
      (__attribute__((address_space(1))) void*)(uintptr_t)g,
      (__attribute__((address_space(3))) void*)(unsigned int)(uintptr_t)l,
      16, 0, 0);
}

// bijective XCD swizzle (m204): consecutive logical ids land on same XCD chunk
DEV int xcd_swz(int flat, int nwg) {
  int q = nwg >> 3, r = nwg & 7;
  int xcd = flat & 7, sid = flat >> 3;
  return (xcd < r ? xcd * (q + 1) : r * (q + 1) + (xcd - r) * q) + sid;
}

// ---------------- transpose + f32->bf16 convert: src[R][Cc] -> dst[Cc][R] ----------------
__global__ __launch_bounds__(256) void transpose_f32_bf16(
    const float* __restrict__ src, u16* __restrict__ dst, int R, int Cc) {
  __shared__ float tile[32][33];
  size_t zoff = (size_t)blockIdx.z * R * Cc;
  const float* s = src + zoff;
  u16* d = dst + zoff;
  int c0 = blockIdx.x * 32, r0 = blockIdx.y * 32;
  int tx = threadIdx.x & 31, ty = threadIdx.x >> 5;
#pragma unroll
  for (int i = 0; i < 4; i++)
    tile[ty + 8 * i][tx] = s[(size_t)(r0 + ty + 8 * i) * Cc + (c0 + tx)];
  __syncthreads();
#pragma unroll
  for (int i = 0; i < 4; i++)
    d[(size_t)(c0 + ty + 8 * i) * R + (r0 + tx)] = f2bf(tile[tx][ty + 8 * i]);
}

// ---------------- bf16 transpose per batch: vb[b*T+t][C] -> vt[b*C+c][T] ----------------
__global__ __launch_bounds__(256) void transpose_v(
    const u16* __restrict__ vb, u16* __restrict__ vt) {
  __shared__ u16 tile[32][33];
  int b = blockIdx.z;
  int t0 = blockIdx.x * 32, c0 = blockIdx.y * 32;
  int tx = threadIdx.x & 31, ty = threadIdx.x >> 5;
#pragma unroll
  for (int i = 0; i < 4; i++)
    tile[ty + 8 * i][tx] = vb[(size_t)(b * T_ + t0 + ty + 8 * i) * C_ + (c0 + tx)];
  __syncthreads();
#pragma unroll
  for (int i = 0; i < 4; i++)
    vt[(size_t)(b * C_ + c0 + ty + 8 * i) * T_ + (t0 + tx)] = tile[tx][ty + 8 * i];
}

// ---------------- embedding ----------------
__global__ __launch_bounds__(256) void embed_kernel(
    const int* __restrict__ idx, const float* __restrict__ tok,
    const float* __restrict__ pos, float* __restrict__ x) {
  int row = blockIdx.x;
  int t = row & (T_ - 1);
  int tk = idx[row];
  const float* tp = tok + (size_t)tk * C_;
  const float* pp = pos + (size_t)t * C_;
  float* xp = x + (size_t)row * C_;
  for (int c = threadIdx.x; c < C_; c += 256) xp[c] = tp[c] + pp[c];
}

// ---------------- layernorm: f32 in -> bf16 out ----------------
__global__ __launch_bounds__(256) void ln_kernel(
    const float* __restrict__ x, const float* __restrict__ g,
    const float* __restrict__ b, u16* __restrict__ out) {
  int row = blockIdx.x;
  int tid = threadIdx.x;
  const float* xp = x + (size_t)row * C_;
  float v0 = xp[tid], v1 = xp[tid + 256], v2 = xp[tid + 512];
  float s = v0 + v1 + v2;
  float ss = v0 * v0 + v1 * v1 + v2 * v2;
#pragma unroll
  for (int o = 32; o > 0; o >>= 1) { s += __shfl_down(s, o); ss += __shfl_down(ss, o); }
  __shared__ float red[8];
  int wid = tid >> 6;
  if ((tid & 63) == 0) { red[wid] = s; red[4 + wid] = ss; }
  __syncthreads();
  float tot = red[0] + red[1] + red[2] + red[3];
  float tss = red[4] + red[5] + red[6] + red[7];
  float mean = tot * (1.f / C_);
  float var = tss * (1.f / C_) - mean * mean;
  float rstd = rsqrtf(var + 1e-5f);
  u16* op = out + (size_t)row * C_;
  op[tid]       = f2bf((v0 - mean) * rstd * g[tid]       + b[tid]);
  op[tid + 256] = f2bf((v1 - mean) * rstd * g[tid + 256] + b[tid + 256]);
  op[tid + 512] = f2bf((v2 - mean) * rstd * g[tid + 512] + b[tid + 512]);
}

// ---------------- GEMM: A[M,K](bf16) @ B[K,N] via BT[N,K](bf16), BK=64 ----------------
// LDS XOR-swizzled (pre-swizzled source + swizzled read). XCD-swizzled grid.
// OUTMODE: 0 = bf16 out, 1 = f32 residual accumulate, 2 = f32 out
template <int BIAS, int RELU, int OUTMODE>
__global__ __launch_bounds__(256) void gemm_bt(
    const u16* __restrict__ A,
    const u16* __restrict__ BT0, const u16* __restrict__ BT1, const u16* __restrict__ BT2,
    const float* __restrict__ bias,
    u16* __restrict__ ob0, u16* __restrict__ ob1, u16* __restrict__ ob2,
    float* __restrict__ fout, int N, int K) {
  const u16* BT = blockIdx.z == 0 ? BT0 : (blockIdx.z == 1 ? BT1 : BT2);
  u16* ob = blockIdx.z == 0 ? ob0 : (blockIdx.z == 1 ? ob1 : ob2);
  __shared__ __align__(16) u16 As[128 * 64];
  __shared__ __align__(16) u16 Bs[128 * 64];
  int tid = threadIdx.x;
  int lane = tid & 63, w = tid >> 6;
  int wm = w >> 1, wn = w & 1;
  int rr = lane & 15, qg = lane >> 4, kq = qg << 3;

  // XCD-aware block remap (x fast within chunk -> same B panel per XCD)
  int gx = gridDim.x;
  int nwg = gx * gridDim.y;
  int flat = blockIdx.y * gx + blockIdx.x;
  int wg = xcd_swz(flat, nwg);
  int m0 = (wg % gx) * 128, n0 = (wg / gx) * 128;

  floatx4 zero = {0.f, 0.f, 0.f, 0.f};
  floatx4 acc[4][4];
#pragma unroll
  for (int i = 0; i < 4; i++)
#pragma unroll
    for (int j = 0; j < 4; j++) acc[i][j] = zero;

  // staging source, pre-swizzled: LDS[d] must hold orig[d ^ (((d>>9)&1)<<5)]
  int d16 = tid * 16;
  int sb = d16 ^ (((d16 >> 9) & 1) << 5);
  int srow = sb >> 7;           // 0..31
  int scol = (sb & 127) >> 1;   // u16 units
  const u16* Ag = A + (size_t)(m0 + srow) * K + scol;
  const u16* Bg = BT + (size_t)(n0 + srow) * K + scol;

  for (int k0 = 0; k0 < K; k0 += 64) {
#pragma unroll
    for (int r4 = 0; r4 < 4; r4++) {
      gload16(Ag + (size_t)(r4 * 32) * K + k0, (char*)As + r4 * 4096 + w * 1024);
      gload16(Bg + (size_t)(r4 * 32) * K + k0, (char*)Bs + r4 * 4096 + w * 1024);
    }
    __syncthreads();
#pragma unroll
    for (int kk = 0; kk < 64; kk += 32) {
      short8 af[4], bf[4];
#pragma unroll
      for (int i = 0; i < 4; i++) {
        int rowA = wm * 64 + i * 16 + rr;
        int ab = rowA * 128 + (kq + kk) * 2; ab ^= ((ab >> 9) & 1) << 5;
        af[i] = *(const short8*)((const char*)As + ab);
        int rowB = wn * 64 + i * 16 + rr;
        int bb = rowB * 128 + (kq + kk) * 2; bb ^= ((bb >> 9) & 1) << 5;
        bf[i] = *(const short8*)((const char*)Bs + bb);
      }
#pragma unroll
      for (int i = 0; i < 4; i++)
#pragma unroll
        for (int j = 0; j < 4; j++)
          acc[i][j] = __builtin_amdgcn_mfma_f32_16x16x32_bf16(af[i], bf[j], acc[i][j], 0, 0, 0);
    }
    __syncthreads();
  }

  int cb = n0 + wn * 64;
  int rb = m0 + wm * 64;
#pragma unroll
  for (int i = 0; i < 4; i++) {
#pragma unroll
    for (int j = 0; j < 4; j++) {
      int col = cb + j * 16 + rr;
      float bv = 0.f;
      if (BIAS) bv = bias[col];
#pragma unroll
      for (int r = 0; r < 4; r++) {
        int row = rb + i * 16 + qg * 4 + r;
        float val = acc[i][j][r] + bv;
        if (RELU) val = fmaxf(val, 0.f);
        size_t o = (size_t)row * N + col;
        if (OUTMODE == 0) ob[o] = f2bf(val);
        else if (OUTMODE == 1) fout[o] += val;
        else fout[o] = val;
      }
    }
  }
}

// ---------------- fused causal attention, swapped-QK^T, lane-local softmax ----------------
// 1 wave per 16 query rows. V pre-transposed: vt[b*C + c][T].
__global__ __launch_bounds__(64) void attn_kernel(
    const u16* __restrict__ q, const u16* __restrict__ k,
    const u16* __restrict__ vt, u16* __restrict__ o) {
  __shared__ __align__(16) u16 P_s[16 * 48];   // pitch 48 u16 = 96 B (16-aligned)
  int nwg = gridDim.x;
  int wg = xcd_swz(blockIdx.x, nwg);
  int qt = wg & 63;            // T/16 = 64 q-tiles
  int h = (wg >> 6) % H_;
  int b = wg / (64 * H_);
  int q0 = qt << 4;
  int lane = threadIdx.x;
  int rr = lane & 15, qg = lane >> 4, kq = qg << 3;

  // Q fragment (B operand): lane holds Q[q0+rr][kq..kq+7 (+32)]
  const u16* qb = q + (size_t)(b * T_ + q0 + rr) * C_ + h * 64;
  short8 qf0 = *(const short8*)(qb + kq);
  short8 qf1 = *(const short8*)(qb + 32 + kq);

  float m_r = -1e30f, l_r = 0.f;   // per-lane: q-row rr
  floatx4 zero = {0.f, 0.f, 0.f, 0.f};
  floatx4 oacc[4];
#pragma unroll
  for (int d = 0; d < 4; d++) oacc[d] = zero;

  const u16* kbase = k + (size_t)(b * T_) * C_ + h * 64;
  const u16* vbase = vt + (size_t)(b * C_ + h * 64) * T_;

  for (int kt0 = 0; kt0 <= q0 + 15; kt0 += 32) {
    // S^T tile: s[c][r] = S[key = kt0 + c*16 + qg*4 + r][q = q0 + rr]
    floatx4 s[2];
#pragma unroll
    for (int c = 0; c < 2; c++) {
      const u16* kb = kbase + (size_t)(kt0 + c * 16 + rr) * C_;
      short8 kf0 = *(const short8*)(kb + kq);
      short8 kf1 = *(const short8*)(kb + 32 + kq);
      floatx4 z = zero;
      z = __builtin_amdgcn_mfma_f32_16x16x32_bf16(kf0, qf0, z, 0, 0, 0);
      z = __builtin_amdgcn_mfma_f32_16x16x32_bf16(kf1, qf1, z, 0, 0, 0);
      s[c] = z;
    }
    int qpos = q0 + rr;
    float p[2][4];
    float mx = -1e30f;
#pragma unroll
    for (int c = 0; c < 2; c++)
#pragma unroll
      for (int r = 0; r < 4; r++) {
        int kpos = kt0 + c * 16 + qg * 4 + r;
        float val = s[c][r] * 0.125f;      // 1/sqrt(64)
        val = (kpos <= qpos) ? val : -1e30f;
        p[c][r] = val;
        mx = fmaxf(mx, val);
      }
    // reduce max over the 4 qg lane-groups holding this q-row
    mx = fmaxf(mx, __shfl_xor(mx, 16));
    mx = fmaxf(mx, __shfl_xor(mx, 32));
    float mn = fmaxf(m_r, mx);
    float escL = exp2f((m_r - mn) * 1.44269504f);
    m_r = mn;
    float ps = 0.f;
#pragma unroll
    for (int c = 0; c < 2; c++)
#pragma unroll
      for (int r = 0; r < 4; r++) {
        float pv = exp2f((p[c][r] - mn) * 1.44269504f);
        p[c][r] = pv;
        ps += pv;
      }
    ps += __shfl_xor(ps, 16);
    ps += __shfl_xor(ps, 32);
    l_r = l_r * escL + ps;
    // write P (bf16) to LDS: P_s[q=rr][k = c*16 + qg*4 + r]
#pragma unroll
    for (int c = 0; c < 2; c++) {
      unsigned int u0 = (unsigned int)f2bf(p[c][0]) | ((unsigned int)f2bf(p[c][1]) << 16);
      unsigned int u1 = (unsigned int)f2bf(p[c][2]) | ((unsigned int)f2bf(p[c][3]) << 16);
      uint2 pk; pk.x = u0; pk.y = u1;
      *(uint2*)&P_s[rr * 48 + c * 16 + qg * 4] = pk;
    }
    // rescale O accumulator: row qg*4+r needs esc of that q-row (lives at lane qg*4+r)
    float er[4];
#pragma unroll
    for (int r = 0; r < 4; r++) er[r] = __shfl(escL, qg * 4 + r);
#pragma unroll
    for (int d = 0; d < 4; d++)
#pragma unroll
      for (int r = 0; r < 4; r++) oacc[d][r] *= er[r];
    // PV: A = P (lane rr = q-row), B = V^T slice (lane rr = d-col)
    short8 pa = *(const short8*)&P_s[rr * 48 + kq];
#pragma unroll
    for (int d = 0; d < 4; d++) {
      short8 vf = *(const short8*)(vbase + (size_t)(d * 16 + rr) * T_ + kt0 + kq);
      oacc[d] = __builtin_amdgcn_mfma_f32_16x16x32_bf16(pa, vf, oacc[d], 0, 0, 0);
    }
  }
  float lb[4];
#pragma unroll
  for (int r = 0; r < 4; r++) lb[r] = __shfl(l_r, qg * 4 + r);
  u16* obp = o + (size_t)(b * T_ + q0) * C_ + h * 64;
#pragma unroll
  for (int d = 0; d < 4; d++)
#pragma unroll
    for (int r = 0; r < 4; r++) {
      int row = qg * 4 + r;
      obp[(size_t)row * C_ + d * 16 + rr] = f2bf(oacc[d][r] / lb[r]);
    }
}

extern "C" void kernel_launch(void* const* d_in, const int* in_sizes, int n_in,
                              void* d_out, int out_size, void* d_ws, size_t ws_size,
                              hipStream_t stream) {
  (void)in_sizes; (void)n_in; (void)out_size; (void)ws_size;
  const int*   xidx = (const int*)d_in[0];
  const float* tok  = (const float*)d_in[1];
  const float* pos  = (const float*)d_in[2];
  const float* ln1g = (const float*)d_in[3];
  const float* ln1b = (const float*)d_in[4];
  const float* wq   = (const float*)d_in[5];
  const float* wk   = (const float*)d_in[6];
  const float* wv   = (const float*)d_in[7];
  const float* wo   = (const float*)d_in[8];
  const float* bo   = (const float*)d_in[9];
  const float* ln2g = (const float*)d_in[10];
  const float* ln2b = (const float*)d_in[11];
  const float* w1   = (const float*)d_in[12];
  const float* b1   = (const float*)d_in[13];
  const float* w2   = (const float*)d_in[14];
  const float* b2   = (const float*)d_in[15];
  const float* lnfg = (const float*)d_in[16];
  const float* lnfb = (const float*)d_in[17];
  const float* wp   = (const float*)d_in[18];
  const float* bp   = (const float*)d_in[19];

  char* ws = (char*)d_ws;
  size_t off = 0;
  auto alloc = [&](size_t bytes) { char* p = ws + off; off += (bytes + 255) & ~(size_t)255; return p; };
  u16* wqT = (u16*)alloc((size_t)L_ * C_ * C_ * 2);
  u16* wkT = (u16*)alloc((size_t)L_ * C_ * C_ * 2);
  u16* wvT = (u16*)alloc((size_t)L_ * C_ * C_ * 2);
  u16* woT = (u16*)alloc((size_t)L_ * C_ * C_ * 2);
  u16* w1T = (u16*)alloc((size_t)L_ * C_ * F_ * 2);
  u16* w2T = (u16*)alloc((size_t)L_ * C_ * F_ * 2);
  u16* wpT = (u16*)alloc((size_t)C_ * V_ * 2);
  float* x = (float*)alloc((size_t)M_ * C_ * 4);
  u16* hb  = (u16*)alloc((size_t)M_ * C_ * 2);
  u16* qb  = (u16*)alloc((size_t)M_ * C_ * 2);
  u16* kb  = (u16*)alloc((size_t)M_ * C_ * 2);
  u16* vb  = (u16*)alloc((size_t)M_ * C_ * 2);
  u16* vtb = (u16*)alloc((size_t)M_ * C_ * 2);
  u16* aob = (u16*)alloc((size_t)M_ * C_ * 2);
  u16* mb  = (u16*)alloc((size_t)M_ * F_ * 2);

  dim3 blk(256);
  transpose_f32_bf16<<<dim3(C_ / 32, C_ / 32, L_), blk, 0, stream>>>(wq, wqT, C_, C_);
  transpose_f32_bf16<<<dim3(C_ / 32, C_ / 32, L_), blk, 0, stream>>>(wk, wkT, C_, C_);
  transpose_f32_bf16<<<dim3(C_ / 32, C_ / 32, L_), blk, 0, stream>>>(wv, wvT, C_, C_);
  transpose_f32_bf16<<<dim3(C_ / 32, C_ / 32, L_), blk, 0, stream>>>(wo, woT, C_, C_);
  transpose_f32_bf16<<<dim3(F_ / 32, C_ / 32, L_), blk, 0, stream>>>(w1, w1T, C_, F_);
  transpose_f32_bf16<<<dim3(C_ / 32, F_ / 32, L_), blk, 0, stream>>>(w2, w2T, F_, C_);
  transpose_f32_bf16<<<dim3(V_ / 32, C_ / 32, 1), blk, 0, stream>>>(wp, wpT, C_, V_);
  embed_kernel<<<M_, blk, 0, stream>>>(xidx, tok, pos, x);

  for (int l = 0; l < L_; ++l) {
    size_t wOff = (size_t)l * C_ * C_;
    size_t fOff = (size_t)l * C_ * F_;
    ln_kernel<<<M_, blk, 0, stream>>>(x, ln1g + l * C_, ln1b + l * C_, hb);
    gemm_bt<0, 0, 0><<<dim3(M_ / 128, C_ / 128, 3), blk, 0, stream>>>(
        hb, wqT + wOff, wkT + wOff, wvT + wOff, nullptr, qb, kb, vb, nullptr, C_, C_);
    transpose_v<<<dim3(T_ / 32, C_ / 32, B_), blk, 0, stream>>>(vb, vtb);
    attn_kernel<<<B_ * H_ * (T_ / 16), dim3(64), 0, stream>>>(qb, kb, vtb, aob);
    gemm_bt<1, 0, 1><<<dim3(M_ / 128, C_ / 128, 1), blk, 0, stream>>>(
        aob, woT + wOff, woT + wOff, woT + wOff, bo + l * C_,
        nullptr, nullptr, nullptr, x, C_, C_);
    ln_kernel<<<M_, blk, 0, stream>>>(x, ln2g + l * C_, ln2b + l * C_, hb);
    gemm_bt<1, 1, 0><<<dim3(M_ / 128, F_ / 128, 1), blk, 0, stream>>>(
        hb, w1T + fOff, w1T + fOff, w1T + fOff, b1 + l * F_,
        mb, mb, mb, nullptr, F_, C_);
    gemm_bt<1, 0, 1><<<dim3(M_ / 128, C_ / 128, 1), blk, 0, stream>>>(
        mb, w2T + fOff, w2T + fOff, w2T + fOff, b2 + l * C_,
        nullptr, nullptr, nullptr, x, C_, F_);
  }
  ln_kernel<<<M_, blk, 0, stream>>>(x, lnfg, lnfb, hb);
  gemm_bt<1, 0, 2><<<dim3(M_ / 128, V_ / 128, 1), blk, 0, stream>>>(
      hb, wpT, wpT, wpT, bp, nullptr, nullptr, nullptr, (float*)d_out, V_, C_);
}

// Round 3
// 1283.868 us; speedup vs baseline: 1.3335x; 1.1794x over previous
//
#include <hip/hip_runtime.h>
#include <stdint.h>

#define DEV __device__ __forceinline__

typedef unsigned short u16;
typedef __attribute__((ext_vector_type(8))) short short8;
typedef __attribute__((ext_vector_type(4))) float floatx4;

#define B_ 2
#define T_ 1024
#define C_ 768
#define H_ 12
#define L_ 6
#define V_ 32000
#define F_ 3072
#define M_ 2048   // B*T
#define C3_ 2304  // 3*C (packed qkv)

#define VMW(n) asm volatile("s_waitcnt vmcnt(" #n ")" ::: "memory")

DEV u16 f2bf(float f) {
  unsigned int u; __builtin_memcpy(&u, &f, 4);
  u += 0x7FFFu + ((u >> 16) & 1u);   // round-to-nearest-even
  return (u16)(u >> 16);
}

// async global->LDS, 16B per lane. LDS ptr must be wave-uniform; HW adds lane*16.
// Global address is per-lane (pre-swizzled source pattern, m173).
DEV void gload16(const void* g, void* l) {
  __builtin_amdgcn_global_load_lds(
      (__attribute__((address_space(1))) void*)(uintptr_t)g,
      (__attribute__((address_space(3))) void*)(unsigned int)(uintptr_t)l,
      16, 0, 0);
}

// bijective XCD swizzle (m204)
DEV int xcd_swz(int flat, int nwg) {
  int q = nwg >> 3, r = nwg & 7;
  int xcd = flat & 7, sid = flat >> 3;
  return (xcd < r ? xcd * (q + 1) : r * (q + 1) + (xcd - r) * q) + sid;
}

// ---------------- transpose + f32->bf16 convert: src[z][R][Cc] -> dst[z*dstz][Cc][R] ----------------
__global__ __launch_bounds__(256) void transpose_f32_bf16(
    const float* __restrict__ src, u16* __restrict__ dst, int R, int Cc,
    size_t src_z, size_t dst_z) {
  __shared__ float tile[32][33];
  const float* s = src + (size_t)blockIdx.z * src_z;
  u16* d = dst + (size_t)blockIdx.z * dst_z;
  int c0 = blockIdx.x * 32, r0 = blockIdx.y * 32;
  int tx = threadIdx.x & 31, ty = threadIdx.x >> 5;
#pragma unroll
  for (int i = 0; i < 4; i++)
    tile[ty + 8 * i][tx] = s[(size_t)(r0 + ty + 8 * i) * Cc + (c0 + tx)];
  __syncthreads();
#pragma unroll
  for (int i = 0; i < 4; i++)
    d[(size_t)(c0 + ty + 8 * i) * R + (r0 + tx)] = f2bf(tile[tx][ty + 8 * i]);
}

// ---------------- bf16 transpose of packed V: qkv[b*T+t][C3_] col1536+c -> vt[b*C+c][T] ----------------
__global__ __launch_bounds__(256) void transpose_v(
    const u16* __restrict__ qkv, u16* __restrict__ vt) {
  __shared__ u16 tile[32][33];
  int b = blockIdx.z;
  int t0 = blockIdx.x * 32, c0 = blockIdx.y * 32;
  int tx = threadIdx.x & 31, ty = threadIdx.x >> 5;
#pragma unroll
  for (int i = 0; i < 4; i++)
    tile[ty + 8 * i][tx] = qkv[(size_t)(b * T_ + t0 + ty + 8 * i) * C3_ + 1536 + c0 + tx];
  __syncthreads();
#pragma unroll
  for (int i = 0; i < 4; i++)
    vt[(size_t)(b * C_ + c0 + ty + 8 * i) * T_ + (t0 + tx)] = tile[tx][ty + 8 * i];
}

// ---------------- embedding ----------------
__global__ __launch_bounds__(256) void embed_kernel(
    const int* __restrict__ idx, const float* __restrict__ tok,
    const float* __restrict__ pos, float* __restrict__ x) {
  int row = blockIdx.x;
  int t = row & (T_ - 1);
  int tk = idx[row];
  const float* tp = tok + (size_t)tk * C_;
  const float* pp = pos + (size_t)t * C_;
  float* xp = x + (size_t)row * C_;
  for (int c = threadIdx.x; c < C_; c += 256) xp[c] = tp[c] + pp[c];
}

// ---------------- layernorm: f32 in -> bf16 out ----------------
__global__ __launch_bounds__(256) void ln_kernel(
    const float* __restrict__ x, const float* __restrict__ g,
    const float* __restrict__ b, u16* __restrict__ out) {
  int row = blockIdx.x;
  int tid = threadIdx.x;
  const float* xp = x + (size_t)row * C_;
  float v0 = xp[tid], v1 = xp[tid + 256], v2 = xp[tid + 512];
  float s = v0 + v1 + v2;
  float ss = v0 * v0 + v1 * v1 + v2 * v2;
#pragma unroll
  for (int o = 32; o > 0; o >>= 1) { s += __shfl_down(s, o); ss += __shfl_down(ss, o); }
  __shared__ float red[8];
  int wid = tid >> 6;
  if ((tid & 63) == 0) { red[wid] = s; red[4 + wid] = ss; }
  __syncthreads();
  float tot = red[0] + red[1] + red[2] + red[3];
  float tss = red[4] + red[5] + red[6] + red[7];
  float mean = tot * (1.f / C_);
  float var = tss * (1.f / C_) - mean * mean;
  float rstd = rsqrtf(var + 1e-5f);
  u16* op = out + (size_t)row * C_;
  op[tid]       = f2bf((v0 - mean) * rstd * g[tid]       + b[tid]);
  op[tid + 256] = f2bf((v1 - mean) * rstd * g[tid + 256] + b[tid + 256]);
  op[tid + 512] = f2bf((v2 - mean) * rstd * g[tid + 512] + b[tid + 512]);
}

// ---------------- GEMM: A[M,K](bf16) @ BT[N,K](bf16), BK=32, 3-deep ring + counted vmcnt ----------------
// Waves: (THREADS/64) as (WM x 2), each owning a 64x64 output tile.
// LDS swizzle: byte ^= (row&3)<<4 (involution; pre-swizzled global source, swizzled read).
// OUTMODE: 0 = bf16 out, 1 = f32 residual accumulate, 2 = f32 out
template <int THREADS, int BM, int BN, int BIAS, int RELU, int OUTMODE>
__global__ __launch_bounds__(THREADS) void gemm3(
    const u16* __restrict__ A, const u16* __restrict__ BT,
    const float* __restrict__ bias,
    u16* __restrict__ ob, float* __restrict__ fout, int N, int K) {
  constexpr int NW = THREADS / 64;
  constexpr int ALOADS = (BM * 64) / (THREADS * 16);
  constexpr int BLOADS = (BN * 64) / (THREADS * 16);
  constexpr int LDS_L = ALOADS + BLOADS;        // loads per iter (3 or 4)
  __shared__ __align__(16) u16 As[3][BM * 32];
  __shared__ __align__(16) u16 Bs[3][BN * 32];

  int tid = threadIdx.x;
  int lane = tid & 63, w = tid >> 6;
  int wm = w >> 1, wn = w & 1;
  int rr = lane & 15, qg = lane >> 4;

  int gx = gridDim.x;
  int nwg = gx * gridDim.y;
  int flat = blockIdx.y * gx + blockIdx.x;
  int wg = xcd_swz(flat, nwg);
  int m0 = (wg % gx) * BM, n0 = (wg / gx) * BN;

  // per-thread pre-swizzled global sources (rule #21: linear LDS dest + inv-swz source + swz read)
  const u16* Aps[ALOADS];
  const u16* Bps[BLOADS];
#pragma unroll
  for (int i = 0; i < ALOADS; i++) {
    int d = i * THREADS * 16 + tid * 16;
    int srow = d >> 6;
    int scolb = (d & 63) ^ ((srow & 3) << 4);
    Aps[i] = A + (size_t)(m0 + srow) * K + (scolb >> 1);
  }
#pragma unroll
  for (int i = 0; i < BLOADS; i++) {
    int d = i * THREADS * 16 + tid * 16;
    int srow = d >> 6;
    int scolb = (d & 63) ^ ((srow & 3) << 4);
    Bps[i] = BT + (size_t)(n0 + srow) * K + (scolb >> 1);
  }

  auto stage = [&](int sl, int k0) {
#pragma unroll
    for (int i = 0; i < ALOADS; i++)
      gload16(Aps[i] + k0, (char*)As + (size_t)sl * BM * 64 + i * THREADS * 16 + w * 1024);
#pragma unroll
    for (int i = 0; i < BLOADS; i++)
      gload16(Bps[i] + k0, (char*)Bs + (size_t)sl * BN * 64 + i * THREADS * 16 + w * 1024);
  };

  floatx4 zero = {0.f, 0.f, 0.f, 0.f};
  floatx4 acc[4][4];
#pragma unroll
  for (int i = 0; i < 4; i++)
#pragma unroll
    for (int j = 0; j < 4; j++) acc[i][j] = zero;

  int NT = K >> 5;
  stage(0, 0);
  stage(1, 32);
  if constexpr (LDS_L == 3) VMW(3); else VMW(4);
  __builtin_amdgcn_s_barrier();
  __builtin_amdgcn_sched_barrier(0);

  for (int t = 0; t < NT; ++t) {
    int sl = t % 3;
    if (t + 2 < NT) stage((t + 2) % 3, (t + 2) << 5);
    __builtin_amdgcn_sched_barrier(0);
    const char* Ab = (const char*)As + (size_t)sl * BM * 64;
    const char* Bb = (const char*)Bs + (size_t)sl * BN * 64;
    short8 af[4], bf[4];
#pragma unroll
    for (int i = 0; i < 4; i++) {
      int rowA = wm * 64 + i * 16 + rr;
      int a = (rowA << 6) + (qg << 4); a ^= (rowA & 3) << 4;
      af[i] = *(const short8*)(Ab + a);
      int rowB = wn * 64 + i * 16 + rr;
      int bb2 = (rowB << 6) + (qg << 4); bb2 ^= (rowB & 3) << 4;
      bf[i] = *(const short8*)(Bb + bb2);
    }
    __builtin_amdgcn_s_setprio(1);
#pragma unroll
    for (int i = 0; i < 4; i++)
#pragma unroll
      for (int j = 0; j < 4; j++)
        acc[i][j] = __builtin_amdgcn_mfma_f32_16x16x32_bf16(af[i], bf[j], acc[i][j], 0, 0, 0);
    __builtin_amdgcn_s_setprio(0);
    if (t < NT - 2) { if constexpr (LDS_L == 3) VMW(3); else VMW(4); }
    else if (t == NT - 2) VMW(0);
    if (t < NT - 1) { __builtin_amdgcn_s_barrier(); __builtin_amdgcn_sched_barrier(0); }
  }

  int cb = n0 + wn * 64;
  int rb = m0 + wm * 64;
#pragma unroll
  for (int i = 0; i < 4; i++) {
#pragma unroll
    for (int j = 0; j < 4; j++) {
      int col = cb + j * 16 + rr;
      float bv = 0.f;
      if (BIAS) bv = bias[col];
#pragma unroll
      for (int r = 0; r < 4; r++) {
        int row = rb + i * 16 + qg * 4 + r;
        float val = acc[i][j][r] + bv;
        if (RELU) val = fmaxf(val, 0.f);
        size_t o = (size_t)row * N + col;
        if (OUTMODE == 0) ob[o] = f2bf(val);
        else if (OUTMODE == 1) fout[o] += val;
        else fout[o] = val;
      }
    }
  }
}

// ---------------- fused causal attention, swapped-QK^T, lane-local softmax ----------------
// 1 wave per 16 query rows. Q/K from packed qkv (row stride C3_); V pre-transposed vt[b*C+c][T].
__global__ __launch_bounds__(64) void attn_kernel(
    const u16* __restrict__ qkv, const u16* __restrict__ vt, u16* __restrict__ o) {
  __shared__ __align__(16) u16 P_s[16 * 48];
  int nwg = gridDim.x;
  int wg = xcd_swz(blockIdx.x, nwg);
  int qt = wg & 63;
  int h = (wg >> 6) % H_;
  int b = wg / (64 * H_);
  int q0 = qt << 4;
  int lane = threadIdx.x;
  int rr = lane & 15, qg = lane >> 4, kq = qg << 3;

  const u16* qb = qkv + (size_t)(b * T_ + q0 + rr) * C3_ + h * 64;
  short8 qf0 = *(const short8*)(qb + kq);
  short8 qf1 = *(const short8*)(qb + 32 + kq);

  float m_r = -1e30f, l_r = 0.f;
  floatx4 zero = {0.f, 0.f, 0.f, 0.f};
  floatx4 oacc[4];
#pragma unroll
  for (int d = 0; d < 4; d++) oacc[d] = zero;

  const u16* kbase = qkv + (size_t)(b * T_) * C3_ + 768 + h * 64;
  const u16* vbase = vt + (size_t)(b * C_ + h * 64) * T_;

  for (int kt0 = 0; kt0 <= q0 + 15; kt0 += 32) {
    floatx4 s[2];
#pragma unroll
    for (int c = 0; c < 2; c++) {
      const u16* kb = kbase + (size_t)(kt0 + c * 16 + rr) * C3_;
      short8 kf0 = *(const short8*)(kb + kq);
      short8 kf1 = *(const short8*)(kb + 32 + kq);
      floatx4 z = zero;
      z = __builtin_amdgcn_mfma_f32_16x16x32_bf16(kf0, qf0, z, 0, 0, 0);
      z = __builtin_amdgcn_mfma_f32_16x16x32_bf16(kf1, qf1, z, 0, 0, 0);
      s[c] = z;
    }
    int qpos = q0 + rr;
    float p[2][4];
    float mx = -1e30f;
#pragma unroll
    for (int c = 0; c < 2; c++)
#pragma unroll
      for (int r = 0; r < 4; r++) {
        int kpos = kt0 + c * 16 + qg * 4 + r;
        float val = s[c][r] * 0.125f;
        val = (kpos <= qpos) ? val : -1e30f;
        p[c][r] = val;
        mx = fmaxf(mx, val);
      }
    mx = fmaxf(mx, __shfl_xor(mx, 16));
    mx = fmaxf(mx, __shfl_xor(mx, 32));
    float mn = fmaxf(m_r, mx);
    float escL = exp2f((m_r - mn) * 1.44269504f);
    m_r = mn;
    float ps = 0.f;
#pragma unroll
    for (int c = 0; c < 2; c++)
#pragma unroll
      for (int r = 0; r < 4; r++) {
        float pv = exp2f((p[c][r] - mn) * 1.44269504f);
        p[c][r] = pv;
        ps += pv;
      }
    ps += __shfl_xor(ps, 16);
    ps += __shfl_xor(ps, 32);
    l_r = l_r * escL + ps;
#pragma unroll
    for (int c = 0; c < 2; c++) {
      unsigned int u0 = (unsigned int)f2bf(p[c][0]) | ((unsigned int)f2bf(p[c][1]) << 16);
      unsigned int u1 = (unsigned int)f2bf(p[c][2]) | ((unsigned int)f2bf(p[c][3]) << 16);
      uint2 pk; pk.x = u0; pk.y = u1;
      *(uint2*)&P_s[rr * 48 + c * 16 + qg * 4] = pk;
    }
    float er[4];
#pragma unroll
    for (int r = 0; r < 4; r++) er[r] = __shfl(escL, qg * 4 + r);
#pragma unroll
    for (int d = 0; d < 4; d++)
#pragma unroll
      for (int r = 0; r < 4; r++) oacc[d][r] *= er[r];
    short8 pa = *(const short8*)&P_s[rr * 48 + kq];
#pragma unroll
    for (int d = 0; d < 4; d++) {
      short8 vf = *(const short8*)(vbase + (size_t)(d * 16 + rr) * T_ + kt0 + kq);
      oacc[d] = __builtin_amdgcn_mfma_f32_16x16x32_bf16(pa, vf, oacc[d], 0, 0, 0);
    }
  }
  float lb[4];
#pragma unroll
  for (int r = 0; r < 4; r++) lb[r] = __shfl(l_r, qg * 4 + r);
  u16* obp = o + (size_t)(b * T_ + q0) * C_ + h * 64;
#pragma unroll
  for (int d = 0; d < 4; d++)
#pragma unroll
    for (int r = 0; r < 4; r++) {
      int row = qg * 4 + r;
      obp[(size_t)row * C_ + d * 16 + rr] = f2bf(oacc[d][r] / lb[r]);
    }
}

extern "C" void kernel_launch(void* const* d_in, const int* in_sizes, int n_in,
                              void* d_out, int out_size, void* d_ws, size_t ws_size,
                              hipStream_t stream) {
  (void)in_sizes; (void)n_in; (void)out_size; (void)ws_size;
  const int*   xidx = (const int*)d_in[0];
  const float* tok  = (const float*)d_in[1];
  const float* pos  = (const float*)d_in[2];
  const float* ln1g = (const float*)d_in[3];
  const float* ln1b = (const float*)d_in[4];
  const float* wq   = (const float*)d_in[5];
  const float* wk   = (const float*)d_in[6];
  const float* wv   = (const float*)d_in[7];
  const float* wo   = (const float*)d_in[8];
  const float* bo   = (const float*)d_in[9];
  const float* ln2g = (const float*)d_in[10];
  const float* ln2b = (const float*)d_in[11];
  const float* w1   = (const float*)d_in[12];
  const float* b1   = (const float*)d_in[13];
  const float* w2   = (const float*)d_in[14];
  const float* b2   = (const float*)d_in[15];
  const float* lnfg = (const float*)d_in[16];
  const float* lnfb = (const float*)d_in[17];
  const float* wp   = (const float*)d_in[18];
  const float* bp   = (const float*)d_in[19];

  char* ws = (char*)d_ws;
  size_t off = 0;
  auto alloc = [&](size_t bytes) { char* p = ws + off; off += (bytes + 255) & ~(size_t)255; return p; };
  u16* wqkvT = (u16*)alloc((size_t)L_ * 3 * C_ * C_ * 2);   // [l][3C][C]
  u16* woT = (u16*)alloc((size_t)L_ * C_ * C_ * 2);
  u16* w1T = (u16*)alloc((size_t)L_ * C_ * F_ * 2);
  u16* w2T = (u16*)alloc((size_t)L_ * C_ * F_ * 2);
  u16* wpT = (u16*)alloc((size_t)C_ * V_ * 2);
  float* x = (float*)alloc((size_t)M_ * C_ * 4);
  u16* hb   = (u16*)alloc((size_t)M_ * C_ * 2);
  u16* qkvb = (u16*)alloc((size_t)M_ * C3_ * 2);
  u16* vtb  = (u16*)alloc((size_t)M_ * C_ * 2);
  u16* aob  = (u16*)alloc((size_t)M_ * C_ * 2);
  u16* mb   = (u16*)alloc((size_t)M_ * F_ * 2);

  dim3 blk(256);
  size_t CC = (size_t)C_ * C_, CF = (size_t)C_ * F_;
  transpose_f32_bf16<<<dim3(C_ / 32, C_ / 32, L_), blk, 0, stream>>>(wq, wqkvT,          C_, C_, CC, 3 * CC);
  transpose_f32_bf16<<<dim3(C_ / 32, C_ / 32, L_), blk, 0, stream>>>(wk, wqkvT + CC,     C_, C_, CC, 3 * CC);
  transpose_f32_bf16<<<dim3(C_ / 32, C_ / 32, L_), blk, 0, stream>>>(wv, wqkvT + 2 * CC, C_, C_, CC, 3 * CC);
  transpose_f32_bf16<<<dim3(C_ / 32, C_ / 32, L_), blk, 0, stream>>>(wo, woT, C_, C_, CC, CC);
  transpose_f32_bf16<<<dim3(F_ / 32, C_ / 32, L_), blk, 0, stream>>>(w1, w1T, C_, F_, CF, CF);
  transpose_f32_bf16<<<dim3(C_ / 32, F_ / 32, L_), blk, 0, stream>>>(w2, w2T, F_, C_, CF, CF);
  transpose_f32_bf16<<<dim3(V_ / 32, C_ / 32, 1), blk, 0, stream>>>(wp, wpT, C_, V_, 0, 0);
  embed_kernel<<<M_, blk, 0, stream>>>(xidx, tok, pos, x);

  for (int l = 0; l < L_; ++l) {
    size_t wOff = (size_t)l * 3 * CC;
    size_t oOff = (size_t)l * CC;
    size_t fOff = (size_t)l * CF;
    ln_kernel<<<M_, blk, 0, stream>>>(x, ln1g + l * C_, ln1b + l * C_, hb);
    gemm3<256, 128, 128, 0, 0, 0><<<dim3(M_ / 128, C3_ / 128), 256, 0, stream>>>(
        hb, wqkvT + wOff, nullptr, qkvb, nullptr, C3_, C_);
    transpose_v<<<dim3(T_ / 32, C_ / 32, B_), blk, 0, stream>>>(qkvb, vtb);
    attn_kernel<<<B_ * H_ * (T_ / 16), dim3(64), 0, stream>>>(qkvb, vtb, aob);
    gemm3<256, 128, 128, 1, 0, 1><<<dim3(M_ / 128, C_ / 128), 256, 0, stream>>>(
        aob, woT + oOff, bo + l * C_, nullptr, x, C_, C_);
    ln_kernel<<<M_, blk, 0, stream>>>(x, ln2g + l * C_, ln2b + l * C_, hb);
    gemm3<256, 128, 128, 1, 1, 0><<<dim3(M_ / 128, F_ / 128), 256, 0, stream>>>(
        hb, w1T + fOff, b1 + l * F_, mb, nullptr, F_, C_);
    gemm3<256, 128, 128, 1, 0, 1><<<dim3(M_ / 128, C_ / 128), 256, 0, stream>>>(
        mb, w2T + fOff, b2 + l * C_, nullptr, x, C_, F_);
  }
  ln_kernel<<<M_, blk, 0, stream>>>(x, lnfg, lnfb, hb);
  gemm3<512, 256, 128, 1, 0, 2><<<dim3(M_ / 256, V_ / 128), 512, 0, stream>>>(
      hb, wpT, bp, nullptr, (float*)d_out, V_, C_);
}